// Round 13
// baseline (816.230 us; speedup 1.0000x reference)
//
#include <hip/hip_runtime.h>
#include <math.h>

#define CH 64
#define S 64
#define S2 (64 * 64)
#define S3 (64 * 64 * 64)

// ---------------------------------------------------------------------------
// Fully-fused conv-attention, single kernel: scores -> softmax -> V-gather ->
// W-projection -> out. Barrier-free, LDS-free. One wave per (b,d,h) row.
//
// Allocation law (r2-r12): ANY __launch_bounds__ min-waves hint triggers
// catastrophic scratch spilling on this kernel family; plain (256) never
// memory-spills. Peak live here ~115 regs (x[64] + weights[27] + ptrs) which
// fits the default allocation the way r4's 136-VGPR kernel did.
// All loads use wave-uniform base pointers bumped by scalar adds + [lane]
// indexing -> SGPR-base + small-VGPR-offset addressing, minimal VALU.
// ---------------------------------------------------------------------------
__global__ __launch_bounds__(256) void attn_fused(const float* __restrict__ Q,
                                                  const float* __restrict__ K,
                                                  const float* __restrict__ V,
                                                  const float* __restrict__ pe,
                                                  const float* __restrict__ Wm,
                                                  const float* __restrict__ bias,
                                                  float* __restrict__ out) {
  int tid = threadIdx.x;
  int lane = tid & 63;
  int wv = tid >> 6;

  // XCD-aware bijective swizzle (2048 % 8 == 0)
  int raw = blockIdx.x;
  int sw = (raw & 7) * 256 + (raw >> 3);
  int b = sw >> 10;
  int r = sw & 1023;
  int d = r >> 4;                                             // 0..63
  int hu = __builtin_amdgcn_readfirstlane((r & 15) * 4 + wv);  // 0..63, uniform

  size_t bbase = (size_t)b << 24;
  const float* Qb = Q + bbase;
  const float* Kb = K + bbase;
  const float* Vb = V + bbase;
  float* outb = out + bbase;

  // per-lane x-pad masks for received shuffles
  float lmL = (lane == 0) ? 0.f : 1.f;
  float lmR = (lane == 63) ? 0.f : 1.f;

  // uniform row offsets (clamped) + OOB masks
  int rowoff[9];
  float okf[9];
#pragma unroll
  for (int dz = 0; dz < 3; ++dz)
#pragma unroll
    for (int dy = 0; dy < 3; ++dy) {
      int rr = dz * 3 + dy;
      int zz = d + dz - 1, yy = hu + dy - 1;
      bool ok = ((unsigned)zz < 64u) & ((unsigned)yy < 64u);
      int zc = zz < 0 ? 0 : (zz > 63 ? 63 : zz);
      int yc = yy < 0 ? 0 : (yy > 63 ? 63 : yy);
      rowoff[rr] = zc * S2 + yc * S;
      okf[rr] = ok ? 1.f : 0.f;
    }
  int upos = d * S2 + hu * S;  // uniform part of this row's base

  float spe[27];  // pe part (always at own lane, unmasked)
  float sC[9], sXR[9], sXL[9];
#pragma unroll
  for (int t = 0; t < 27; ++t) spe[t] = 0.f;
#pragma unroll
  for (int rr = 0; rr < 9; ++rr) { sC[rr] = 0.f; sXR[rr] = 0.f; sXL[rr] = 0.f; }

  // ---- Phase A: scores (2 shuffles/channel; uniform ptr bumps) ----
  {
    const float* k0 = Kb + rowoff[0]; const float* k1 = Kb + rowoff[1];
    const float* k2 = Kb + rowoff[2]; const float* k3 = Kb + rowoff[3];
    const float* k4 = Kb + rowoff[4]; const float* k5 = Kb + rowoff[5];
    const float* k6 = Kb + rowoff[6]; const float* k7 = Kb + rowoff[7];
    const float* k8 = Kb + rowoff[8];
    const float* qp = Qb + upos;
    const float* pec = pe;
#pragma unroll 4
    for (int c = 0; c < CH; ++c) {
      float q = qp[lane];
      float rv[9];
      rv[0] = k0[lane]; rv[1] = k1[lane]; rv[2] = k2[lane];
      rv[3] = k3[lane]; rv[4] = k4[lane]; rv[5] = k5[lane];
      rv[6] = k6[lane]; rv[7] = k7[lane]; rv[8] = k8[lane];
      qp += S3;
      k0 += S3; k1 += S3; k2 += S3; k3 += S3; k4 += S3;
      k5 += S3; k6 += S3; k7 += S3; k8 += S3;
      float qR = __shfl_down(q, 1);  // q of lane+1
      float qL = __shfl_up(q, 1);    // q of lane-1
#pragma unroll
      for (int rr = 0; rr < 9; ++rr) {
        sC[rr]  = fmaf(q,  rv[rr], sC[rr]);
        sXR[rr] = fmaf(qR, rv[rr], sXR[rr]);  // belongs to lane+1's left tap
        sXL[rr] = fmaf(qL, rv[rr], sXL[rr]);  // belongs to lane-1's right tap
      }
#pragma unroll
      for (int t = 0; t < 27; ++t) spe[t] = fmaf(q, pec[t], spe[t]);
      pec += 27;
    }
  }

  // ---- assemble the 27 tap scores (18 shuffles, once) ----
  float s[27];
#pragma unroll
  for (int rr = 0; rr < 9; ++rr) {
    float lt = __shfl_up(sXR[rr], 1);    // = sum_c q[w]*K[rr][w-1]
    float rt = __shfl_down(sXL[rr], 1);  // = sum_c q[w]*K[rr][w+1]
    s[rr * 3]     = fmaf(lt * lmL, okf[rr], spe[rr * 3]);
    s[rr * 3 + 1] = fmaf(sC[rr],   okf[rr], spe[rr * 3 + 1]);
    s[rr * 3 + 2] = fmaf(rt * lmR, okf[rr], spe[rr * 3 + 2]);
  }

  // ---- softmax over 27 taps (base-2; normalization folded into weights) ----
  const float SC = 0.125f * 1.44269504088896f;
#pragma unroll
  for (int t = 0; t < 27; ++t) s[t] *= SC;
  float m = s[0];
#pragma unroll
  for (int t = 1; t < 27; ++t) m = fmaxf(m, s[t]);
  float sum = 0.f;
#pragma unroll
  for (int t = 0; t < 27; ++t) {
    s[t] = exp2f(s[t] - m);
    sum += s[t];
  }
  float inv = 1.f / sum;

  // ---- weights: fold inv + row mask; pre-shuffle cross weights ----
  float wC[9], sLs[9], sRs[9];
#pragma unroll
  for (int rr = 0; rr < 9; ++rr) {
    float f = inv * okf[rr];  // OOB rows: V-pad = 0 -> weight 0
    float wL = s[rr * 3] * f;
    wC[rr]   = s[rr * 3 + 1] * f;
    float wR = s[rr * 3 + 2] * f;
    sLs[rr] = __shfl_down(wL, 1);  // left-tap weight of lane+1
    sRs[rr] = __shfl_up(wR, 1);    // right-tap weight of lane-1
  }

  // ---- Phase B1: gather x[c] once (fully unrolled, all-static indices;
  //      uniform pointer bumps) ----
  float x[CH];
  {
    const float* p0 = Vb + rowoff[0]; const float* p1 = Vb + rowoff[1];
    const float* p2 = Vb + rowoff[2]; const float* p3 = Vb + rowoff[3];
    const float* p4 = Vb + rowoff[4]; const float* p5 = Vb + rowoff[5];
    const float* p6 = Vb + rowoff[6]; const float* p7 = Vb + rowoff[7];
    const float* p8 = Vb + rowoff[8];
#pragma unroll
    for (int c = 0; c < CH; ++c) {
      float rv[9];
      rv[0] = p0[lane]; rv[1] = p1[lane]; rv[2] = p2[lane];
      rv[3] = p3[lane]; rv[4] = p4[lane]; rv[5] = p5[lane];
      rv[6] = p6[lane]; rv[7] = p7[lane]; rv[8] = p8[lane];
      p0 += S3; p1 += S3; p2 += S3; p3 += S3; p4 += S3;
      p5 += S3; p6 += S3; p7 += S3; p8 += S3;
      float own = 0.f, cR = 0.f, cL = 0.f;
#pragma unroll
      for (int rr = 0; rr < 9; ++rr) {
        own = fmaf(wC[rr], rv[rr], own);
        cR  = fmaf(sLs[rr], rv[rr], cR);  // contribution to x of lane+1
        cL  = fmaf(sRs[rr], rv[rr], cL);  // contribution to x of lane-1
      }
      x[c] = own + __shfl_up(cR, 1) * lmL + __shfl_down(cL, 1) * lmR;
    }
  }

  // ---- Phase B2: projection, o-outer, immediate stores (no acc array).
  //      W row contiguous -> wide s_loads; 4-way split accumulators. ----
  {
    const float* wr = Wm;
    float* op = outb + upos;
#pragma unroll 2
    for (int o = 0; o < CH; ++o) {
      float a0 = 0.f, a1 = 0.f, a2 = 0.f, a3 = 0.f;
#pragma unroll
      for (int c = 0; c < CH; c += 4) {
        a0 = fmaf(wr[c],     x[c],     a0);
        a1 = fmaf(wr[c + 1], x[c + 1], a1);
        a2 = fmaf(wr[c + 2], x[c + 2], a2);
        a3 = fmaf(wr[c + 3], x[c + 3], a3);
      }
      op[lane] = ((a0 + a1) + (a2 + a3)) + bias[o];
      wr += CH;
      op += S3;
    }
  }
}

// ---------------------------------------------------------------------------
extern "C" void kernel_launch(void* const* d_in, const int* in_sizes, int n_in,
                              void* d_out, int out_size, void* d_ws, size_t ws_size,
                              hipStream_t stream) {
  const float* Q = (const float*)d_in[0];
  const float* K = (const float*)d_in[1];
  const float* V = (const float*)d_in[2];
  const float* pe = (const float*)d_in[3];
  const float* W = (const float*)d_in[4];
  const float* bias = (const float*)d_in[5];
  float* out = (float*)d_out;

  attn_fused<<<2048, 256, 0, stream>>>(Q, K, V, pe, W, bias, out);
}

// Round 14
// 474.865 us; speedup vs baseline: 1.7189x; 1.7189x over previous
//
#include <hip/hip_runtime.h>
#include <math.h>

#define CH 64
#define S 64
#define S2 (64 * 64)
#define S3 (64 * 64 * 64)

__device__ float WT_buf[CH * CH];  // W transposed: WT[c][o]

// ---------------------------------------------------------------------------
// Kernel 0: transpose W (64x64) into WT_buf.
// ---------------------------------------------------------------------------
__global__ __launch_bounds__(256) void wtrans(const float* __restrict__ W) {
  int i = blockIdx.x * 256 + threadIdx.x;
  int o = i >> 6, c = i & 63;
  WT_buf[c * CH + o] = W[o * CH + c];
}

// ---------------------------------------------------------------------------
// Kernel 1: attn_x — scores -> softmax -> single-pass V-gather -> x (d_ws).
// Barrier-free, LDS-free, plain launch bounds (r2-r13 law: min-waves hints
// cause scratch spills; big live panels cause AGPR-parking/occupancy death —
// this kernel has neither: peak live ~60-90 regs).
// One wave per (b,d,h) row; lane = w. 128-thread blocks (2 waves), grid 4096
// for finer dispatch granularity than r7's 2048x256 (tail imbalance).
// ---------------------------------------------------------------------------
__global__ __launch_bounds__(128) void attn_x(const float* __restrict__ Q,
                                              const float* __restrict__ K,
                                              const float* __restrict__ V,
                                              const float* __restrict__ pe,
                                              float* __restrict__ xout) {
  int tid = threadIdx.x;
  int lane = tid & 63;
  int wv = tid >> 6;

  // XCD-aware bijective swizzle (4096 % 8 == 0)
  int raw = blockIdx.x;
  int sw = (raw & 7) * 512 + (raw >> 3);
  int b = sw >> 11;
  int r = sw & 2047;
  int d = r >> 5;                                             // 0..63
  int hu = __builtin_amdgcn_readfirstlane((r & 31) * 2 + wv);  // 0..63, uniform

  size_t bbase = (size_t)b << 24;
  const float* Qb = Q + bbase;
  const float* Kb = K + bbase;
  const float* Vb = V + bbase;
  float* xo = xout + bbase;

  // per-lane x-pad masks for received shuffles
  float lmL = (lane == 0) ? 0.f : 1.f;
  float lmR = (lane == 63) ? 0.f : 1.f;

  // uniform row offsets (clamped) + OOB masks
  int rowoff[9];
  float okf[9];
#pragma unroll
  for (int dz = 0; dz < 3; ++dz)
#pragma unroll
    for (int dy = 0; dy < 3; ++dy) {
      int rr = dz * 3 + dy;
      int zz = d + dz - 1, yy = hu + dy - 1;
      bool ok = ((unsigned)zz < 64u) & ((unsigned)yy < 64u);
      int zc = zz < 0 ? 0 : (zz > 63 ? 63 : zz);
      int yc = yy < 0 ? 0 : (yy > 63 ? 63 : yy);
      rowoff[rr] = zc * S2 + yc * S;
      okf[rr] = ok ? 1.f : 0.f;
    }
  int upos = d * S2 + hu * S;  // uniform part of this row's base

  float spe[27];  // pe part (always at own lane, unmasked)
  float sC[9], sXR[9], sXL[9];
#pragma unroll
  for (int t = 0; t < 27; ++t) spe[t] = 0.f;
#pragma unroll
  for (int rr = 0; rr < 9; ++rr) { sC[rr] = 0.f; sXR[rr] = 0.f; sXL[rr] = 0.f; }

  // ---- Phase A: scores (2 shuffles/channel; uniform ptr bumps) ----
  {
    const float* k0 = Kb + rowoff[0]; const float* k1 = Kb + rowoff[1];
    const float* k2 = Kb + rowoff[2]; const float* k3 = Kb + rowoff[3];
    const float* k4 = Kb + rowoff[4]; const float* k5 = Kb + rowoff[5];
    const float* k6 = Kb + rowoff[6]; const float* k7 = Kb + rowoff[7];
    const float* k8 = Kb + rowoff[8];
    const float* qp = Qb + upos;
    const float* pec = pe;
#pragma unroll 4
    for (int c = 0; c < CH; ++c) {
      float q = qp[lane];
      float rv[9];
      rv[0] = k0[lane]; rv[1] = k1[lane]; rv[2] = k2[lane];
      rv[3] = k3[lane]; rv[4] = k4[lane]; rv[5] = k5[lane];
      rv[6] = k6[lane]; rv[7] = k7[lane]; rv[8] = k8[lane];
      qp += S3;
      k0 += S3; k1 += S3; k2 += S3; k3 += S3; k4 += S3;
      k5 += S3; k6 += S3; k7 += S3; k8 += S3;
      float qR = __shfl_down(q, 1);  // q of lane+1
      float qL = __shfl_up(q, 1);    // q of lane-1
#pragma unroll
      for (int rr = 0; rr < 9; ++rr) {
        sC[rr]  = fmaf(q,  rv[rr], sC[rr]);
        sXR[rr] = fmaf(qR, rv[rr], sXR[rr]);  // belongs to lane+1's left tap
        sXL[rr] = fmaf(qL, rv[rr], sXL[rr]);  // belongs to lane-1's right tap
      }
#pragma unroll
      for (int t = 0; t < 27; ++t) spe[t] = fmaf(q, pec[t], spe[t]);
      pec += 27;
    }
  }

  // ---- assemble the 27 tap scores (18 shuffles, once) ----
  float s[27];
#pragma unroll
  for (int rr = 0; rr < 9; ++rr) {
    float lt = __shfl_up(sXR[rr], 1);    // = sum_c q[w]*K[rr][w-1]
    float rt = __shfl_down(sXL[rr], 1);  // = sum_c q[w]*K[rr][w+1]
    s[rr * 3]     = fmaf(lt * lmL, okf[rr], spe[rr * 3]);
    s[rr * 3 + 1] = fmaf(sC[rr],   okf[rr], spe[rr * 3 + 1]);
    s[rr * 3 + 2] = fmaf(rt * lmR, okf[rr], spe[rr * 3 + 2]);
  }

  // ---- softmax over 27 taps (base-2; normalization folded into weights) ----
  const float SC = 0.125f * 1.44269504088896f;
#pragma unroll
  for (int t = 0; t < 27; ++t) s[t] *= SC;
  float m = s[0];
#pragma unroll
  for (int t = 1; t < 27; ++t) m = fmaxf(m, s[t]);
  float sum = 0.f;
#pragma unroll
  for (int t = 0; t < 27; ++t) {
    s[t] = exp2f(s[t] - m);
    sum += s[t];
  }
  float inv = 1.f / sum;

  // ---- weights: fold inv + row mask; pre-shuffle cross weights ----
  float wC[9], sLs[9], sRs[9];
#pragma unroll
  for (int rr = 0; rr < 9; ++rr) {
    float f = inv * okf[rr];  // OOB rows: V-pad = 0 -> weight 0
    float wL = s[rr * 3] * f;
    wC[rr]   = s[rr * 3 + 1] * f;
    float wR = s[rr * 3 + 2] * f;
    sLs[rr] = __shfl_down(wL, 1);  // left-tap weight of lane+1
    sRs[rr] = __shfl_up(wR, 1);    // right-tap weight of lane-1
  }

  // ---- Phase B: single-pass gather, store x immediately (no live panel) ----
  {
    const float* p0 = Vb + rowoff[0]; const float* p1 = Vb + rowoff[1];
    const float* p2 = Vb + rowoff[2]; const float* p3 = Vb + rowoff[3];
    const float* p4 = Vb + rowoff[4]; const float* p5 = Vb + rowoff[5];
    const float* p6 = Vb + rowoff[6]; const float* p7 = Vb + rowoff[7];
    const float* p8 = Vb + rowoff[8];
    float* xp = xo + upos;
#pragma unroll 4
    for (int c = 0; c < CH; ++c) {
      float rv[9];
      rv[0] = p0[lane]; rv[1] = p1[lane]; rv[2] = p2[lane];
      rv[3] = p3[lane]; rv[4] = p4[lane]; rv[5] = p5[lane];
      rv[6] = p6[lane]; rv[7] = p7[lane]; rv[8] = p8[lane];
      p0 += S3; p1 += S3; p2 += S3; p3 += S3; p4 += S3;
      p5 += S3; p6 += S3; p7 += S3; p8 += S3;
      float own = 0.f, cR = 0.f, cL = 0.f;
#pragma unroll
      for (int rr = 0; rr < 9; ++rr) {
        own = fmaf(wC[rr], rv[rr], own);
        cR  = fmaf(sLs[rr], rv[rr], cR);  // contribution to x of lane+1
        cL  = fmaf(sRs[rr], rv[rr], cL);  // contribution to x of lane-1
      }
      xp[lane] = own + __shfl_up(cR, 1) * lmL + __shfl_down(cL, 1) * lmR;
      xp += S3;
    }
  }
}

// ---------------------------------------------------------------------------
// Kernel 2: proj — out[o,p] = sum_c WT[c][o] * x[c,p] + bias[o].
// Each wave owns 64 consecutive positions and a PRIVATE LDS panel [64][64]:
// thread t writes slot [c][t] and later re-reads ONLY [c][t] (same address ->
// compiler-ordered, no barriers, conflict-free). o-tiled: acc[16] live only.
// ---------------------------------------------------------------------------
__global__ __launch_bounds__(256) void proj(const float* __restrict__ x,
                                            const float* __restrict__ bias,
                                            float* __restrict__ out) {
  __shared__ float xs[4][CH][64];  // 65.5 KB
  int tid = threadIdx.x, lane = tid & 63, wv = tid >> 6;
  int grp = blockIdx.x * 4 + wv;       // wave index: 0..8191
  int b = grp >> 12;                   // 4096 waves per batch
  int pos = (grp & 4095) << 6;         // 64 consecutive positions per wave
  size_t base = ((size_t)b << 24) + pos + lane;
  const float* xb = x + base;
  float* xw = &xs[wv][0][0];

  // stage this wave's 64 x-rows (coalesced) into the private panel
#pragma unroll 8
  for (int c = 0; c < CH; ++c) xw[c * 64 + lane] = xb[(size_t)c << 18];

  float* outp = out + base;
#pragma unroll 1
  for (int ot = 0; ot < 4; ++ot) {
    float acc[16];
#pragma unroll
    for (int j = 0; j < 16; ++j) acc[j] = 0.f;
#pragma unroll 4
    for (int c = 0; c < CH; ++c) {
      float xc = xw[c * 64 + lane];          // same address this thread wrote
      const float* wr = WT_buf + c * CH + ot * 16;  // uniform -> wide s_load
#pragma unroll
      for (int j = 0; j < 16; ++j) acc[j] = fmaf(wr[j], xc, acc[j]);
    }
#pragma unroll
    for (int j = 0; j < 16; ++j)
      outp[(size_t)(ot * 16 + j) << 18] = acc[j] + bias[ot * 16 + j];
  }
}

// ---------------------------------------------------------------------------
extern "C" void kernel_launch(void* const* d_in, const int* in_sizes, int n_in,
                              void* d_out, int out_size, void* d_ws, size_t ws_size,
                              hipStream_t stream) {
  const float* Q = (const float*)d_in[0];
  const float* K = (const float*)d_in[1];
  const float* V = (const float*)d_in[2];
  const float* pe = (const float*)d_in[3];
  const float* W = (const float*)d_in[4];
  const float* bias = (const float*)d_in[5];
  float* out = (float*)d_out;
  float* xbuf = (float*)d_ws;  // 134 MB scratch: x[b][c][p]

  wtrans<<<16, 256, 0, stream>>>(W);
  attn_x<<<4096, 128, 0, stream>>>(Q, K, V, pe, xbuf);
  proj<<<2048, 256, 0, stream>>>(xbuf, bias, out);
}

// Round 15
// 310.563 us; speedup vs baseline: 2.6282x; 1.5290x over previous
//
#include <hip/hip_runtime.h>
#include <math.h>

#define CH 64
#define S 64
#define S2 (64 * 64)
#define S3 (64 * 64 * 64)

__device__ float WT_buf[CH * CH];  // W transposed: WT[c][o]

// ---------------------------------------------------------------------------
// Kernel 0: transpose W (64x64) into WT_buf.
// ---------------------------------------------------------------------------
__global__ __launch_bounds__(256) void wtrans(const float* __restrict__ W) {
  int i = blockIdx.x * 256 + threadIdx.x;
  int o = i >> 6, c = i & 63;
  WT_buf[c * CH + o] = W[o * CH + c];
}

// ---------------------------------------------------------------------------
// Kernel 1: attn_x — scores -> softmax -> single-pass V-gather -> x (d_ws).
// Structure = r7's measured-204us kernel verbatim (256-thr blocks, grid 2048,
// krow-array addressing); only phase B's source (V instead of Y=W@V) and the
// destination (x in d_ws) differ. Plain launch bounds (min-waves hints cause
// spills, r2-r13). Barrier-free, LDS-free; one wave per (b,d,h) row.
// ---------------------------------------------------------------------------
__global__ __launch_bounds__(256) void attn_x(const float* __restrict__ Q,
                                              const float* __restrict__ K,
                                              const float* __restrict__ V,
                                              const float* __restrict__ pe,
                                              float* __restrict__ xout) {
  int tid = threadIdx.x;
  int lane = tid & 63;
  int wv = tid >> 6;

  // XCD-aware bijective swizzle (2048 % 8 == 0)
  int raw = blockIdx.x;
  int sw = (raw & 7) * 256 + (raw >> 3);
  int b = sw >> 10;
  int r = sw & 1023;
  int d = r >> 4;                                             // 0..63
  int hu = __builtin_amdgcn_readfirstlane((r & 15) * 4 + wv);  // 0..63, uniform

  size_t bbase = (size_t)b << 24;
  const float* Qb = Q + bbase;
  const float* Kb = K + bbase;
  const float* Vb = V + bbase;
  float* xo = xout + bbase;

  // per-lane x-pad masks for received shuffles
  float lmL = (lane == 0) ? 0.f : 1.f;
  float lmR = (lane == 63) ? 0.f : 1.f;

  // uniform row bases (clamped) + OOB masks
  const float* krow[9];
  const float* vrow[9];
  float okf[9];
#pragma unroll
  for (int dz = 0; dz < 3; ++dz)
#pragma unroll
    for (int dy = 0; dy < 3; ++dy) {
      int rr = dz * 3 + dy;
      int zz = d + dz - 1, yy = hu + dy - 1;
      bool ok = ((unsigned)zz < 64u) & ((unsigned)yy < 64u);
      int zc = zz < 0 ? 0 : (zz > 63 ? 63 : zz);
      int yc = yy < 0 ? 0 : (yy > 63 ? 63 : yy);
      krow[rr] = Kb + zc * S2 + yc * S;
      vrow[rr] = Vb + zc * S2 + yc * S;
      okf[rr] = ok ? 1.f : 0.f;
    }
  int pos = d * S2 + hu * S + lane;

  float spe[27];  // pe part (always at own lane, unmasked)
  float sC[9], sXR[9], sXL[9];
#pragma unroll
  for (int t = 0; t < 27; ++t) spe[t] = 0.f;
#pragma unroll
  for (int rr = 0; rr < 9; ++rr) { sC[rr] = 0.f; sXR[rr] = 0.f; sXL[rr] = 0.f; }

  // ---- Phase A: scores (2 shuffles per channel) ----
#pragma unroll 4
  for (int c = 0; c < CH; ++c) {
    int coff = c * S3;
    float q = Qb[coff + pos];
    float rv[9];
#pragma unroll
    for (int rr = 0; rr < 9; ++rr) rv[rr] = krow[rr][coff + lane];
    float qR = __shfl_down(q, 1);  // q of lane+1
    float qL = __shfl_up(q, 1);    // q of lane-1
#pragma unroll
    for (int rr = 0; rr < 9; ++rr) {
      sC[rr]  = fmaf(q,  rv[rr], sC[rr]);
      sXR[rr] = fmaf(qR, rv[rr], sXR[rr]);  // belongs to lane+1's left tap
      sXL[rr] = fmaf(qL, rv[rr], sXL[rr]);  // belongs to lane-1's right tap
    }
    const float* pec = pe + c * 27;  // uniform -> scalar loads
#pragma unroll
    for (int t = 0; t < 27; ++t) spe[t] = fmaf(q, pec[t], spe[t]);
  }

  // ---- assemble the 27 tap scores (18 shuffles, once) ----
  float s[27];
#pragma unroll
  for (int rr = 0; rr < 9; ++rr) {
    float lt = __shfl_up(sXR[rr], 1);    // = sum_c q[w]*K[rr][w-1]
    float rt = __shfl_down(sXL[rr], 1);  // = sum_c q[w]*K[rr][w+1]
    s[rr * 3]     = fmaf(lt * lmL, okf[rr], spe[rr * 3]);
    s[rr * 3 + 1] = fmaf(sC[rr],   okf[rr], spe[rr * 3 + 1]);
    s[rr * 3 + 2] = fmaf(rt * lmR, okf[rr], spe[rr * 3 + 2]);
  }

  // ---- softmax over 27 taps (base-2; normalization folded into weights) ----
  const float SC = 0.125f * 1.44269504088896f;
#pragma unroll
  for (int t = 0; t < 27; ++t) s[t] *= SC;
  float m = s[0];
#pragma unroll
  for (int t = 1; t < 27; ++t) m = fmaxf(m, s[t]);
  float sum = 0.f;
#pragma unroll
  for (int t = 0; t < 27; ++t) {
    s[t] = exp2f(s[t] - m);
    sum += s[t];
  }
  float inv = 1.f / sum;

  // ---- weights: fold inv + row mask; pre-shuffle cross weights ----
  float wC[9], sLs[9], sRs[9];
#pragma unroll
  for (int rr = 0; rr < 9; ++rr) {
    float f = inv * okf[rr];  // OOB rows: V-pad = 0 -> weight 0
    float wL = s[rr * 3] * f;
    wC[rr]   = s[rr * 3 + 1] * f;
    float wR = s[rr * 3 + 2] * f;
    sLs[rr] = __shfl_down(wL, 1);  // left-tap weight of lane+1
    sRs[rr] = __shfl_up(wR, 1);    // right-tap weight of lane-1
  }

  // ---- Phase B: single-pass V-gather, store x immediately (2 shuffles/ch) ----
#pragma unroll 2
  for (int c = 0; c < CH; ++c) {
    int coff = c * S3;
    float rv[9];
#pragma unroll
    for (int rr = 0; rr < 9; ++rr) rv[rr] = vrow[rr][coff + lane];
    float own = 0.f, cR = 0.f, cL = 0.f;
#pragma unroll
    for (int rr = 0; rr < 9; ++rr) {
      own = fmaf(wC[rr], rv[rr], own);
      cR  = fmaf(sLs[rr], rv[rr], cR);  // contribution to x of lane+1
      cL  = fmaf(sRs[rr], rv[rr], cL);  // contribution to x of lane-1
    }
    xo[coff + pos] = own + __shfl_up(cR, 1) * lmL + __shfl_down(cL, 1) * lmR;
  }
}

// ---------------------------------------------------------------------------
// Kernel 2: proj — out[o,p] = sum_c WT[c][o] * x[c,p] + bias[o].
// Each wave owns 64 consecutive positions and a PRIVATE LDS panel [64][64]:
// thread t writes slot [c][t] and later re-reads ONLY [c][t] (same address ->
// compiler-ordered, no barriers, conflict-free). o-tiled: acc[16] live only.
// Proven no-spill at ~60us (r12/r14).
// ---------------------------------------------------------------------------
__global__ __launch_bounds__(256) void proj(const float* __restrict__ x,
                                            const float* __restrict__ bias,
                                            float* __restrict__ out) {
  __shared__ float xs[4][CH][64];  // 65.5 KB
  int tid = threadIdx.x, lane = tid & 63, wv = tid >> 6;
  int grp = blockIdx.x * 4 + wv;       // wave index: 0..8191
  int b = grp >> 12;                   // 4096 waves per batch
  int pos = (grp & 4095) << 6;         // 64 consecutive positions per wave
  size_t base = ((size_t)b << 24) + pos + lane;
  const float* xb = x + base;
  float* xw = &xs[wv][0][0];

  // stage this wave's 64 x-rows (coalesced) into the private panel
#pragma unroll 8
  for (int c = 0; c < CH; ++c) xw[c * 64 + lane] = xb[(size_t)c << 18];

  float* outp = out + base;
#pragma unroll 1
  for (int ot = 0; ot < 4; ++ot) {
    float acc[16];
#pragma unroll
    for (int j = 0; j < 16; ++j) acc[j] = 0.f;
#pragma unroll 4
    for (int c = 0; c < CH; ++c) {
      float xc = xw[c * 64 + lane];          // same address this thread wrote
      const float* wr = WT_buf + c * CH + ot * 16;  // uniform -> wide s_load
#pragma unroll
      for (int j = 0; j < 16; ++j) acc[j] = fmaf(wr[j], xc, acc[j]);
    }
#pragma unroll
    for (int j = 0; j < 16; ++j)
      outp[(size_t)(ot * 16 + j) << 18] = acc[j] + bias[ot * 16 + j];
  }
}

// ---------------------------------------------------------------------------
extern "C" void kernel_launch(void* const* d_in, const int* in_sizes, int n_in,
                              void* d_out, int out_size, void* d_ws, size_t ws_size,
                              hipStream_t stream) {
  const float* Q = (const float*)d_in[0];
  const float* K = (const float*)d_in[1];
  const float* V = (const float*)d_in[2];
  const float* pe = (const float*)d_in[3];
  const float* W = (const float*)d_in[4];
  const float* bias = (const float*)d_in[5];
  float* out = (float*)d_out;
  float* xbuf = (float*)d_ws;  // 134 MB scratch: x[b][c][p]

  wtrans<<<16, 256, 0, stream>>>(W);
  attn_x<<<2048, 256, 0, stream>>>(Q, K, V, pe, xbuf);
  proj<<<2048, 256, 0, stream>>>(xbuf, bias, out);
}